// Round 13
// baseline (229.217 us; speedup 1.0000x reference)
//
#include <hip/hip_runtime.h>

#define P_CNT 32768
#define D_DIM 256
#define B_SZ  256
#define INVT  20.0f          // 1/TEMP
#define NEG_BIG -3.0e38f
#define SLICE_N 4096
#define NSLICE 8
#define CAPC 512
#define CAPS 512
#define TC 2.5f              // cross candidate threshold (score)
#define TS 0.40f             // sims candidate threshold
#define MREF 4.5f            // intra LSE fixed reference (> any score max)

typedef _Float16 half8  __attribute__((ext_vector_type(8)));
typedef _Float16 half4v __attribute__((ext_vector_type(4)));
typedef float    floatx4 __attribute__((ext_vector_type(4)));

__device__ __forceinline__ unsigned fkey(float v) {
  unsigned bu = __float_as_uint(v);
  return bu ^ ((unsigned)(((int)bu) >> 31) | 0x80000000u);
}
__device__ __forceinline__ float fdec(unsigned k) {
  unsigned bu = (k & 0x80000000u) ? (k ^ 0x80000000u) : ~k;
  return __uint_as_float(bu);
}

__device__ __forceinline__ float blockSum4(float v, int tid, float* red4) {
#pragma unroll
  for (int off = 1; off < 64; off <<= 1) v += __shfl_xor(v, off);
  if ((tid & 63) == 0) red4[tid >> 6] = v;
  __syncthreads();
  float r = red4[0] + red4[1] + red4[2] + red4[3];
  __syncthreads();
  return r;
}

__device__ __forceinline__ int blockSumI4(int v, int tid, int* redI) {
#pragma unroll
  for (int off = 1; off < 64; off <<= 1) v += __shfl_xor(v, off);
  if ((tid & 63) == 0) redI[tid >> 6] = v;
  __syncthreads();
  int r = redI[0] + redI[1] + redI[2] + redI[3];
  __syncthreads();
  return r;
}

// ---------------- kernel 0: gather prx, build A' = [features; mem[prx]] ----------------
__global__ void prep_kernel(const float* __restrict__ features,
                            const int* __restrict__ targets,
                            const int* __restrict__ all_prx,
                            const float* __restrict__ mem,
                            float* __restrict__ A2,
                            int* __restrict__ prxArr) {
  const int b = blockIdx.x;
  const int k = threadIdx.x;
  const int t = targets[b];
  const int pr = all_prx[t];
  if (k == 0) prxArr[b] = pr;
  A2[b * D_DIM + k] = features[b * D_DIM + k];
  A2[(B_SZ + b) * D_DIM + k] = mem[(size_t)pr * D_DIM + k];
}

// ---------------- kernel 1: split-fp16 3-pass MFMA GEMM ----------------
__global__ __launch_bounds__(256) void gemm_mfma(const float* __restrict__ A,
                                                 const float* __restrict__ Bm,
                                                 float* __restrict__ Co) {
  __shared__ _Float16 Ah[128][32], Al[128][32], Bh[128][32], Bl[128][32];
  const int tid = threadIdx.x;
  const int lane = tid & 63;
  const int wid = tid >> 6;
  const int wr = wid >> 1, wc = wid & 1;
  const int orig = (blockIdx.x & 7) * 128 + (blockIdx.x >> 3);
  const int rowBase = (orig & 3) << 7;
  const int colBase = (orig >> 2) << 7;

  const int trow = tid >> 3;
  const int tseg = tid & 7;

  floatx4 acc[4][4];
#pragma unroll
  for (int i = 0; i < 4; ++i)
#pragma unroll
    for (int j = 0; j < 4; ++j) {
      acc[i][j][0] = 0.f; acc[i][j][1] = 0.f; acc[i][j][2] = 0.f; acc[i][j][3] = 0.f;
    }

  const int fr = lane & 15;
  const int kg = (lane >> 4) << 3;

  for (int step = 0; step < 8; ++step) {
    const int k0 = step << 5;
    float4 sa[4], sb[4];
#pragma unroll
    for (int p = 0; p < 4; ++p) {
      const int r = trow + (p << 5);
      sa[p] = *(const float4*)(A  + (size_t)(rowBase + r) * D_DIM + k0 + tseg * 4);
      sb[p] = *(const float4*)(Bm + (size_t)(colBase + r) * D_DIM + k0 + tseg * 4);
    }
    __syncthreads();
#pragma unroll
    for (int p = 0; p < 4; ++p) {
      const int r = trow + (p << 5);
      float4 v = sa[p];
      half4v h, l;
      h[0] = (_Float16)v.x; l[0] = (_Float16)(v.x - (float)h[0]);
      h[1] = (_Float16)v.y; l[1] = (_Float16)(v.y - (float)h[1]);
      h[2] = (_Float16)v.z; l[2] = (_Float16)(v.z - (float)h[2]);
      h[3] = (_Float16)v.w; l[3] = (_Float16)(v.w - (float)h[3]);
      *(half4v*)&Ah[r][tseg * 4] = h;
      *(half4v*)&Al[r][tseg * 4] = l;
      v = sb[p];
      h[0] = (_Float16)v.x; l[0] = (_Float16)(v.x - (float)h[0]);
      h[1] = (_Float16)v.y; l[1] = (_Float16)(v.y - (float)h[1]);
      h[2] = (_Float16)v.z; l[2] = (_Float16)(v.z - (float)h[2]);
      h[3] = (_Float16)v.w; l[3] = (_Float16)(v.w - (float)h[3]);
      *(half4v*)&Bh[r][tseg * 4] = h;
      *(half4v*)&Bl[r][tseg * 4] = l;
    }
    __syncthreads();
    half8 ah[4], al[4], bh[4], bl[4];
#pragma unroll
    for (int f = 0; f < 4; ++f) {
      ah[f] = *(const half8*)&Ah[wr * 64 + f * 16 + fr][kg];
      al[f] = *(const half8*)&Al[wr * 64 + f * 16 + fr][kg];
      bh[f] = *(const half8*)&Bh[wc * 64 + f * 16 + fr][kg];
      bl[f] = *(const half8*)&Bl[wc * 64 + f * 16 + fr][kg];
    }
#pragma unroll
    for (int fm = 0; fm < 4; ++fm)
#pragma unroll
      for (int fn = 0; fn < 4; ++fn) {
        acc[fm][fn] = __builtin_amdgcn_mfma_f32_16x16x32_f16(ah[fm], bh[fn], acc[fm][fn], 0, 0, 0);
        acc[fm][fn] = __builtin_amdgcn_mfma_f32_16x16x32_f16(ah[fm], bl[fn], acc[fm][fn], 0, 0, 0);
        acc[fm][fn] = __builtin_amdgcn_mfma_f32_16x16x32_f16(al[fm], bh[fn], acc[fm][fn], 0, 0, 0);
      }
  }
  const int rsub = (lane >> 4) << 2;
#pragma unroll
  for (int fm = 0; fm < 4; ++fm)
#pragma unroll
    for (int fn = 0; fn < 4; ++fn) {
      const int r0 = rowBase + wr * 64 + fm * 16 + rsub;
      const int c0 = colBase + wc * 64 + fn * 16 + fr;
#pragma unroll
      for (int r = 0; r < 4; ++r)
        Co[(size_t)(r0 + r) * P_CNT + c0] = acc[fm][fn][r];
    }
}

// ---------------- kernel STATS: streaming per-slice stats + threshold appends ------
// 2048 blocks (8 slices x 256 samples) x 256 thr; 1 barrier.
// Thread owns p = s*4096 + 4*tid + 1024*q + c,  q in [0,4), c in [0,4).
__global__ __launch_bounds__(256) void stats(
    const float* __restrict__ OUT, const int* __restrict__ cams,
    const int* __restrict__ prxArr,
    unsigned* __restrict__ maxKey, float* __restrict__ intraS,
    unsigned long long* __restrict__ camSlot,
    int* __restrict__ cxCnt, float* __restrict__ cxVal, int* __restrict__ cxIdx,
    int* __restrict__ smCnt, float* __restrict__ smVal, int* __restrict__ smIdx) {
  __shared__ float redM[4], redE[4];
  const int blk = blockIdx.x;
  const int b = blk >> 3, s = blk & 7;
  const int tid = threadIdx.x, lane = tid & 63, wid = tid >> 6;
  const float* Srow = OUT + (size_t)b * P_CNT + s * SLICE_N;
  const float* Mrow = OUT + (size_t)(B_SZ + b) * P_CNT + s * SLICE_N;
  const int pr = prxArr[b], cam = cams[b];
  const int posBase = pr & ~7;
  const int gbase = s * SLICE_N + 4 * tid;

  // load score slice
  float sc[16];
#pragma unroll
  for (int q = 0; q < 4; ++q) {
    float4 f = ((const float4*)Srow)[tid + 256 * q];
    sc[4 * q + 0] = f.x; sc[4 * q + 1] = f.y; sc[4 * q + 2] = f.z; sc[4 * q + 3] = f.w;
  }
  float pmax = sc[0];
#pragma unroll
  for (int j = 1; j < 16; ++j) pmax = fmaxf(pmax, sc[j]);

  // intra partial: fixed-ref exp-sum over {p : p%8 == cam}
  float ei = 0.f;
  if ((tid & 1) == (cam >> 2)) {
    const int cc = cam & 3;
#pragma unroll
    for (int q = 0; q < 4; ++q) {
      float v = (cc == 0) ? sc[4 * q] : (cc == 1) ? sc[4 * q + 1]
              : (cc == 2) ? sc[4 * q + 2] : sc[4 * q + 3];
      ei += expf((v - MREF) * INVT);
    }
  }
#pragma unroll
  for (int off = 1; off < 64; off <<= 1) {
    pmax = fmaxf(pmax, __shfl_xor(pmax, off));
    ei += __shfl_xor(ei, off);
  }
  if (lane == 0) { redM[wid] = pmax; redE[wid] = ei; }

  // cross candidate appends (score > TC, pos excluded)
#pragma unroll
  for (int j = 0; j < 16; ++j) {
    float v = sc[j];
    if (v > TC) {
      int p = gbase + ((j >> 2) << 10) + (j & 3);
      if ((unsigned)(p - posBase) >= 8u) {
        int t = atomicAdd(&cxCnt[b], 1);
        if (t < CAPC) { cxVal[(size_t)b * CAPC + t] = v; cxIdx[(size_t)b * CAPC + t] = p; }
      }
    }
  }

  // sims
  float sm[16];
#pragma unroll
  for (int q = 0; q < 4; ++q) {
    float4 g = ((const float4*)Mrow)[tid + 256 * q];
    sm[4 * q + 0] = 0.15f * sc[4 * q + 0] + 0.85f * g.x;
    sm[4 * q + 1] = 0.15f * sc[4 * q + 1] + 0.85f * g.y;
    sm[4 * q + 2] = 0.15f * sc[4 * q + 2] + 0.85f * g.z;
    sm[4 * q + 3] = 0.15f * sc[4 * q + 3] + 0.85f * g.w;
  }
#pragma unroll
  for (int j = 0; j < 16; ++j) {
    float v = sm[j];
    if (v > TS) {
      int p = gbase + ((j >> 2) << 10) + (j & 3);
      int t = atomicAdd(&smCnt[b], 1);
      if (t < CAPS) { smVal[(size_t)b * CAPS + t] = v; smIdx[(size_t)b * CAPS + t] = p; }
    }
  }

  // per-cam argmax: thread's col c has cam (4*(tid&1)+c); exact via packed u64
  {
    unsigned long long pk[4];
#pragma unroll
    for (int c = 0; c < 4; ++c) {
      float bv = sm[c]; int bp = gbase + c;
#pragma unroll
      for (int q = 1; q < 4; ++q) {
        float v = sm[4 * q + c];
        int p = gbase + (q << 10) + c;
        if (v > bv) { bv = v; bp = p; }
      }
      pk[c] = ((unsigned long long)fkey(bv) << 32) | (unsigned)(~(unsigned)bp);
    }
#pragma unroll
    for (int off = 2; off <= 32; off <<= 1) {
#pragma unroll
      for (int c = 0; c < 4; ++c) {
        unsigned long long o = __shfl_xor(pk[c], off);
        if (o > pk[c]) pk[c] = o;
      }
    }
    if (lane < 2) {
#pragma unroll
      for (int c = 0; c < 4; ++c)
        atomicMax(&camSlot[b * 8 + lane * 4 + c], pk[c]);
    }
  }
  __syncthreads();
  if (tid == 0) {
    float m = fmaxf(fmaxf(redM[0], redM[1]), fmaxf(redM[2], redM[3]));
    atomicMax(&maxKey[b], fkey(m));
  }
  if (tid == 1) atomicAdd(&intraS[b], redE[0] + redE[1] + redE[2] + redE[3]);
}

// ---------------- helper: block count of elements above threshold -------------
__device__ int countAbove(const float* Srow, const float* Mrow, int mode,
                          float T, int posBase, int tid, int* redI) {
  int c = 0;
  for (int i = tid; i < P_CNT; i += 256) {
    float v = (mode == 0) ? Srow[i] : (0.15f * Srow[i] + 0.85f * Mrow[i]);
    bool ok = (mode == 0) ? ((unsigned)(i - posBase) >= 8u) : true;
    if (ok && v > T) c++;
  }
  return blockSumI4(c, tid, redI);
}

// ---------------- kernel FIXUP: exact fallback if counts out of range ---------
// Always launched; early-exits when stats thresholds were valid (expected case).
__global__ __launch_bounds__(256) void fixup(
    const float* __restrict__ OUT, const int* __restrict__ prxArr,
    const unsigned* __restrict__ maxKey,
    int* __restrict__ cxCnt, float* __restrict__ cxVal, int* __restrict__ cxIdx,
    int* __restrict__ smCnt, float* __restrict__ smVal, int* __restrict__ smIdx) {
  __shared__ int redI[4];
  const int b = blockIdx.x;
  const int tid = threadIdx.x;
  const float* Srow = OUT + (size_t)b * P_CNT;
  const float* Mrow = OUT + (size_t)(B_SZ + b) * P_CNT;
  const int posBase = prxArr[b] & ~7;

  // ---- cross list fix ----
  int cc = cxCnt[b];
  if (cc < 50 || cc > CAPC) {
    float M = fdec(maxKey[b]);
    float lo = M - 1.0f;
    int c = countAbove(Srow, Mrow, 0, lo, posBase, tid, redI);
    for (int it = 0; it < 24 && c < 50; ++it) {
      lo -= (M - lo);
      c = countAbove(Srow, Mrow, 0, lo, posBase, tid, redI);
    }
    float hi = M;
    for (int it = 0; it < 32 && c > CAPC; ++it) {
      float mid = 0.5f * (lo + hi);
      int cm = countAbove(Srow, Mrow, 0, mid, posBase, tid, redI);
      if (cm >= 50) { lo = mid; c = cm; } else hi = mid;
    }
    if (tid == 0) cxCnt[b] = 0;
    __syncthreads();
    for (int i = tid; i < P_CNT; i += 256) {
      float v = Srow[i];
      if (v > lo && (unsigned)(i - posBase) >= 8u) {
        int t = atomicAdd(&cxCnt[b], 1);
        if (t < CAPC) { cxVal[(size_t)b * CAPC + t] = v; cxIdx[(size_t)b * CAPC + t] = i; }
      }
    }
    __syncthreads();
    if (tid == 0) { if (cxCnt[b] > CAPC) cxCnt[b] = CAPC; }
  }
  __syncthreads();

  // ---- sims list fix ----
  int sc2 = smCnt[b];
  if (sc2 < 53 || sc2 > CAPS) {
    // find sims max for bracketing
    float mx = NEG_BIG;
    for (int i = tid; i < P_CNT; i += 256)
      mx = fmaxf(mx, 0.15f * Srow[i] + 0.85f * Mrow[i]);
#pragma unroll
    for (int off = 1; off < 64; off <<= 1) mx = fmaxf(mx, __shfl_xor(mx, off));
    if ((tid & 63) == 0) redI[tid >> 6] = __float_as_int(mx);
    __syncthreads();
    float M = fmaxf(fmaxf(__int_as_float(redI[0]), __int_as_float(redI[1])),
                    fmaxf(__int_as_float(redI[2]), __int_as_float(redI[3])));
    __syncthreads();
    float lo = M - 0.3f;
    int c = countAbove(Srow, Mrow, 1, lo, posBase, tid, redI);
    for (int it = 0; it < 24 && c < 53; ++it) {
      lo -= (M - lo);
      c = countAbove(Srow, Mrow, 1, lo, posBase, tid, redI);
    }
    float hi = M;
    for (int it = 0; it < 32 && c > CAPS; ++it) {
      float mid = 0.5f * (lo + hi);
      int cm = countAbove(Srow, Mrow, 1, mid, posBase, tid, redI);
      if (cm >= 53) { lo = mid; c = cm; } else hi = mid;
    }
    if (tid == 0) smCnt[b] = 0;
    __syncthreads();
    for (int i = tid; i < P_CNT; i += 256) {
      float v = 0.15f * Srow[i] + 0.85f * Mrow[i];
      if (v > lo) {
        int t = atomicAdd(&smCnt[b], 1);
        if (t < CAPS) { smVal[(size_t)b * CAPS + t] = v; smIdx[(size_t)b * CAPS + t] = i; }
      }
    }
    __syncthreads();
    if (tid == 0) { if (smCnt[b] > CAPS) smCnt[b] = CAPS; }
  }
}

// ---------------- kernel MERGE: per-sample exact rank + losses (256 blocks) ----
__global__ __launch_bounds__(256) void merge(
    const float* __restrict__ OUT, const int* __restrict__ prxArr,
    const unsigned* __restrict__ maxKey, const float* __restrict__ intraS,
    const unsigned long long* __restrict__ camSlot,
    const int* __restrict__ cxCnt, const float* __restrict__ cxVal,
    const int* __restrict__ cxIdx,
    const int* __restrict__ smCnt, const float* __restrict__ smVal,
    const int* __restrict__ smIdx,
    float* __restrict__ intraArr, float* __restrict__ crossArr,
    float* __restrict__ onlArr) {
  __shared__ __align__(16) float vb[CAPC + 4];
  __shared__ __align__(16) int   ib[CAPC + 4];
  __shared__ __align__(16) float vs[CAPS + 4];
  __shared__ __align__(16) int   is_[CAPS + 4];
  __shared__ float red4[4];
  __shared__ int ch[3];
  __shared__ float sbuf[56];
  __shared__ int scnt;

  const int b = blockIdx.x;
  const int tid = threadIdx.x;
  const float* Srow = OUT + (size_t)b * P_CNT;
  const int pr = prxArr[b];
  const int posBase = pr & ~7;
  const int C = min(cxCnt[b], CAPC);
  const int C2 = min(smCnt[b], CAPS);
  const int Cp = (C + 3) & ~3;
  const int C2p = (C2 + 3) & ~3;

  // ---- phase A: stage lists + scalars ----
  for (int i = tid; i < C; i += 256) {
    vb[i] = cxVal[(size_t)b * CAPC + i];
    ib[i] = cxIdx[(size_t)b * CAPC + i];
  }
  for (int i = tid; i < C2; i += 256) {
    vs[i] = smVal[(size_t)b * CAPS + i];
    is_[i] = smIdx[(size_t)b * CAPS + i];
  }
  if (tid >= 240 && tid < 244) {
    int i = C + (tid - 240);
    if (i < Cp) { vb[i] = NEG_BIG; ib[i] = 0x7fffffff; }
  }
  if (tid >= 244 && tid < 248) {
    int i = C2 + (tid - 244);
    if (i < C2p) { vs[i] = NEG_BIG; is_[i] = 0x7fffffff; }
  }
  if (tid == 96) {   // cam top-3 (packed u64 ordering = (value, smaller idx))
    unsigned long long sl[8];
#pragma unroll
    for (int c = 0; c < 8; ++c) sl[c] = camSlot[b * 8 + c];
    unsigned used = 0;
    for (int k = 0; k < 3; ++k) {
      unsigned long long best = 0; int bc = 0;
      for (int c = 0; c < 8; ++c)
        if (!((used >> c) & 1u) && sl[c] > best) { best = sl[c]; bc = c; }
      used |= 1u << bc;
      ch[k] = (int)(~(unsigned)(best & 0xffffffffull));
    }
  }
  if (tid == 97) intraArr[b] = -((Srow[pr] - MREF) * INVT - logf(intraS[b]));
  if (tid == 98) scnt = 0;
  __syncthreads();

  // ---- phase B: mask chosen in sims list ----
  const int c0 = ch[0], c1 = ch[1], c2 = ch[2];
  for (int i = tid; i < C2; i += 256) {
    int ix = is_[i];
    if (ix == c0 || ix == c1 || ix == c2) vs[i] = NEG_BIG;
  }
  __syncthreads();

  const float M = fdec(maxKey[b]);

  // ---- phase C1: sims rank (2 candidates/thread) -> winners gather ----
  {
    float v0 = (tid < C2) ? vs[tid] : NEG_BIG;
    int   i0 = (tid < C2) ? is_[tid] : 0x7fffffff;
    float v1 = (tid + 256 < C2) ? vs[tid + 256] : NEG_BIG;
    int   i1 = (tid + 256 < C2) ? is_[tid + 256] : 0x7fffffff;
    int r0 = 0, r1 = 0;
    const float4* v4 = (const float4*)vs;
    const int4*   q4 = (const int4*)is_;
    for (int m4 = 0; m4 < (C2p >> 2); ++m4) {
      float4 vm = v4[m4]; int4 im = q4[m4];
      r0 += (vm.x > v0) || (vm.x == v0 && im.x < i0);
      r0 += (vm.y > v0) || (vm.y == v0 && im.y < i0);
      r0 += (vm.z > v0) || (vm.z == v0 && im.z < i0);
      r0 += (vm.w > v0) || (vm.w == v0 && im.w < i0);
      r1 += (vm.x > v1) || (vm.x == v1 && im.x < i1);
      r1 += (vm.y > v1) || (vm.y == v1 && im.y < i1);
      r1 += (vm.z > v1) || (vm.z == v1 && im.z < i1);
      r1 += (vm.w > v1) || (vm.w == v1 && im.w < i1);
    }
    if (tid < C2 && v0 > -1.0e38f && r0 < 50) {
      int t = atomicAdd(&scnt, 1);
      if (t < 50) sbuf[t] = Srow[i0];
    }
    if (tid + 256 < C2 && v1 > -1.0e38f && r1 < 50) {
      int t = atomicAdd(&scnt, 1);
      if (t < 50) sbuf[t] = Srow[i1];
    }
    if (tid < 3) sbuf[50 + tid] = Srow[ch[tid]];
  }

  // ---- phase C2: cross rank (2/thread) -> exp-sum ----
  float myexp = 0.f, pl = 0.f;
  {
    float v0 = (tid < C) ? vb[tid] : NEG_BIG;
    int   i0 = (tid < C) ? ib[tid] : 0x7fffffff;
    float v1 = (tid + 256 < C) ? vb[tid + 256] : NEG_BIG;
    int   i1 = (tid + 256 < C) ? ib[tid + 256] : 0x7fffffff;
    int r0 = 0, r1 = 0;
    const float4* v4 = (const float4*)vb;
    const int4*   q4 = (const int4*)ib;
    for (int m4 = 0; m4 < (Cp >> 2); ++m4) {
      float4 vm = v4[m4]; int4 im = q4[m4];
      r0 += (vm.x > v0) || (vm.x == v0 && im.x < i0);
      r0 += (vm.y > v0) || (vm.y == v0 && im.y < i0);
      r0 += (vm.z > v0) || (vm.z == v0 && im.z < i0);
      r0 += (vm.w > v0) || (vm.w == v0 && im.w < i0);
      r1 += (vm.x > v1) || (vm.x == v1 && im.x < i1);
      r1 += (vm.y > v1) || (vm.y == v1 && im.y < i1);
      r1 += (vm.z > v1) || (vm.z == v1 && im.z < i1);
      r1 += (vm.w > v1) || (vm.w == v1 && im.w < i1);
    }
    if (tid < C && r0 < 50) myexp += expf((v0 - M) * INVT);
    if (tid + 256 < C && r1 < 50) myexp += expf((v1 - M) * INVT);
    if (tid < 8) {
      float pv = Srow[posBase + tid];
      myexp += expf((pv - M) * INVT);
      pl = (pv - M) * INVT;
    }
  }
  float stot = blockSum4(myexp, tid, red4);
  float plin = blockSum4(pl, tid, red4);
  if (tid == 0) {
    float lse = logf(stot);
    crossArr[b] = -(plin - 8.f * lse) * 0.125f;
  }

  // ---- phase D: online LSE over 53 (sbuf complete: written before blockSum barriers)
  if (tid < 64) {
    float v = (tid < 53) ? sbuf[tid] : NEG_BIG;
    float mm = v;
#pragma unroll
    for (int off = 1; off < 64; off <<= 1) mm = fmaxf(mm, __shfl_xor(mm, off));
    float e = (tid < 53) ? expf((v - mm) * INVT) : 0.f;
    float ss = e;
#pragma unroll
    for (int off = 1; off < 64; off <<= 1) ss += __shfl_xor(ss, off);
    float lse = logf(ss);
    float c = (tid >= 50 && tid < 53) ? ((v - mm) * INVT - lse) : 0.f;
#pragma unroll
    for (int off = 1; off < 64; off <<= 1) c += __shfl_xor(c, off);
    if (tid == 0) onlArr[b] = -c * (1.0f / 3.0f);
  }
}

// ---------------- kernel 3: per-camera means -> scalar ----------------
__global__ void finalize(const int* __restrict__ cams,
                         const float* __restrict__ ia,
                         const float* __restrict__ ca,
                         const float* __restrict__ oa,
                         float* __restrict__ out) {
  if (blockIdx.x == 0 && threadIdx.x == 0) {
    float s[8] = {}; float n[8] = {};
    for (int b = 0; b < B_SZ; ++b) {
      int c = cams[b];
      s[c] += ia[b] + ca[b] + oa[b];
      n[c] += 1.f;
    }
    float tot = 0.f;
    for (int c = 0; c < 8; ++c)
      if (n[c] > 0.f) tot += s[c] / n[c];
    out[0] = tot;
  }
}

extern "C" void kernel_launch(void* const* d_in, const int* in_sizes, int n_in,
                              void* d_out, int out_size, void* d_ws, size_t ws_size,
                              hipStream_t stream) {
  const float* features = (const float*)d_in[0];
  const int*   targets  = (const int*)d_in[1];
  const int*   cams     = (const int*)d_in[2];
  const float* mem      = (const float*)d_in[4];
  const int*   all_prx  = (const int*)d_in[6];

  float* ws = (float*)d_ws;
  float* A2  = ws;                               // 512*256
  float* OUT = ws + 512 * D_DIM;                 // 512*32768
  char*  tail = (char*)(OUT + (size_t)512 * P_CNT);

  int*      prxArr = (int*)tail;                tail += B_SZ * 4;
  // ---- zero-init block (memset below): ----
  char* zbase = tail;
  unsigned* maxKey = (unsigned*)tail;           tail += B_SZ * 4;
  float*    intraS = (float*)tail;              tail += B_SZ * 4;
  unsigned long long* camSlot = (unsigned long long*)tail; tail += B_SZ * 8 * 8;
  int* cxCnt = (int*)tail;                      tail += B_SZ * 4;
  int* smCnt = (int*)tail;                      tail += B_SZ * 4;
  size_t zbytes = (size_t)(tail - zbase);
  // ---- end zero block ----
  float* intraArr = (float*)tail;               tail += B_SZ * 4;
  float* crossArr = (float*)tail;               tail += B_SZ * 4;
  float* onlArr   = (float*)tail;               tail += B_SZ * 4;
  float* cxVal = (float*)tail;                  tail += (size_t)B_SZ * CAPC * 4;
  int*   cxIdx = (int*)tail;                    tail += (size_t)B_SZ * CAPC * 4;
  float* smVal = (float*)tail;                  tail += (size_t)B_SZ * CAPS * 4;
  int*   smIdx = (int*)tail;                    tail += (size_t)B_SZ * CAPS * 4;

  hipMemsetAsync(zbase, 0, zbytes, stream);
  prep_kernel<<<B_SZ, D_DIM, 0, stream>>>(features, targets, all_prx, mem, A2, prxArr);
  gemm_mfma<<<1024, 256, 0, stream>>>(A2, mem, OUT);
  stats<<<B_SZ * NSLICE, 256, 0, stream>>>(OUT, cams, prxArr,
      maxKey, intraS, camSlot, cxCnt, cxVal, cxIdx, smCnt, smVal, smIdx);
  fixup<<<B_SZ, 256, 0, stream>>>(OUT, prxArr, maxKey,
      cxCnt, cxVal, cxIdx, smCnt, smVal, smIdx);
  merge<<<B_SZ, 256, 0, stream>>>(OUT, prxArr, maxKey, intraS, camSlot,
      cxCnt, cxVal, cxIdx, smCnt, smVal, smIdx, intraArr, crossArr, onlArr);
  finalize<<<1, 64, 0, stream>>>(cams, intraArr, crossArr, onlArr, (float*)d_out);
}

// Round 14
// 148.007 us; speedup vs baseline: 1.5487x; 1.5487x over previous
//
#include <hip/hip_runtime.h>

#define P_CNT 32768
#define D_DIM 256
#define B_SZ  256
#define INVT  20.0f          // 1/TEMP
#define NEG_BIG -3.0e38f
#define SLICE_N 4096
#define NSLICE 8
#define CAPC 512
#define CAPS 512
#define CAPB 160             // per-block LDS candidate cap (expected ~25)
#define TC 2.5f              // cross candidate threshold (score)
#define TS 0.40f             // sims candidate threshold
#define MREF 4.5f            // intra LSE fixed reference (> any score max)

typedef _Float16 half8  __attribute__((ext_vector_type(8)));
typedef _Float16 half4v __attribute__((ext_vector_type(4)));
typedef float    floatx4 __attribute__((ext_vector_type(4)));

__device__ __forceinline__ unsigned fkey(float v) {
  unsigned bu = __float_as_uint(v);
  return bu ^ ((unsigned)(((int)bu) >> 31) | 0x80000000u);
}
__device__ __forceinline__ float fdec(unsigned k) {
  unsigned bu = (k & 0x80000000u) ? (k ^ 0x80000000u) : ~k;
  return __uint_as_float(bu);
}

__device__ __forceinline__ float blockSum4(float v, int tid, float* red4) {
#pragma unroll
  for (int off = 1; off < 64; off <<= 1) v += __shfl_xor(v, off);
  if ((tid & 63) == 0) red4[tid >> 6] = v;
  __syncthreads();
  float r = red4[0] + red4[1] + red4[2] + red4[3];
  __syncthreads();
  return r;
}

__device__ __forceinline__ int blockSumI4(int v, int tid, int* redI) {
#pragma unroll
  for (int off = 1; off < 64; off <<= 1) v += __shfl_xor(v, off);
  if ((tid & 63) == 0) redI[tid >> 6] = v;
  __syncthreads();
  int r = redI[0] + redI[1] + redI[2] + redI[3];
  __syncthreads();
  return r;
}

// ---------------- kernel 0: gather prx, build A' = [features; mem[prx]] ----------------
__global__ void prep_kernel(const float* __restrict__ features,
                            const int* __restrict__ targets,
                            const int* __restrict__ all_prx,
                            const float* __restrict__ mem,
                            float* __restrict__ A2,
                            int* __restrict__ prxArr) {
  const int b = blockIdx.x;
  const int k = threadIdx.x;
  const int t = targets[b];
  const int pr = all_prx[t];
  if (k == 0) prxArr[b] = pr;
  A2[b * D_DIM + k] = features[b * D_DIM + k];
  A2[(B_SZ + b) * D_DIM + k] = mem[(size_t)pr * D_DIM + k];
}

// ---------------- kernel 1: split-fp16 3-pass MFMA GEMM ----------------
__global__ __launch_bounds__(256) void gemm_mfma(const float* __restrict__ A,
                                                 const float* __restrict__ Bm,
                                                 float* __restrict__ Co) {
  __shared__ _Float16 Ah[128][32], Al[128][32], Bh[128][32], Bl[128][32];
  const int tid = threadIdx.x;
  const int lane = tid & 63;
  const int wid = tid >> 6;
  const int wr = wid >> 1, wc = wid & 1;
  const int orig = (blockIdx.x & 7) * 128 + (blockIdx.x >> 3);
  const int rowBase = (orig & 3) << 7;
  const int colBase = (orig >> 2) << 7;

  const int trow = tid >> 3;
  const int tseg = tid & 7;

  floatx4 acc[4][4];
#pragma unroll
  for (int i = 0; i < 4; ++i)
#pragma unroll
    for (int j = 0; j < 4; ++j) {
      acc[i][j][0] = 0.f; acc[i][j][1] = 0.f; acc[i][j][2] = 0.f; acc[i][j][3] = 0.f;
    }

  const int fr = lane & 15;
  const int kg = (lane >> 4) << 3;

  for (int step = 0; step < 8; ++step) {
    const int k0 = step << 5;
    float4 sa[4], sb[4];
#pragma unroll
    for (int p = 0; p < 4; ++p) {
      const int r = trow + (p << 5);
      sa[p] = *(const float4*)(A  + (size_t)(rowBase + r) * D_DIM + k0 + tseg * 4);
      sb[p] = *(const float4*)(Bm + (size_t)(colBase + r) * D_DIM + k0 + tseg * 4);
    }
    __syncthreads();
#pragma unroll
    for (int p = 0; p < 4; ++p) {
      const int r = trow + (p << 5);
      float4 v = sa[p];
      half4v h, l;
      h[0] = (_Float16)v.x; l[0] = (_Float16)(v.x - (float)h[0]);
      h[1] = (_Float16)v.y; l[1] = (_Float16)(v.y - (float)h[1]);
      h[2] = (_Float16)v.z; l[2] = (_Float16)(v.z - (float)h[2]);
      h[3] = (_Float16)v.w; l[3] = (_Float16)(v.w - (float)h[3]);
      *(half4v*)&Ah[r][tseg * 4] = h;
      *(half4v*)&Al[r][tseg * 4] = l;
      v = sb[p];
      h[0] = (_Float16)v.x; l[0] = (_Float16)(v.x - (float)h[0]);
      h[1] = (_Float16)v.y; l[1] = (_Float16)(v.y - (float)h[1]);
      h[2] = (_Float16)v.z; l[2] = (_Float16)(v.z - (float)h[2]);
      h[3] = (_Float16)v.w; l[3] = (_Float16)(v.w - (float)h[3]);
      *(half4v*)&Bh[r][tseg * 4] = h;
      *(half4v*)&Bl[r][tseg * 4] = l;
    }
    __syncthreads();
    half8 ah[4], al[4], bh[4], bl[4];
#pragma unroll
    for (int f = 0; f < 4; ++f) {
      ah[f] = *(const half8*)&Ah[wr * 64 + f * 16 + fr][kg];
      al[f] = *(const half8*)&Al[wr * 64 + f * 16 + fr][kg];
      bh[f] = *(const half8*)&Bh[wc * 64 + f * 16 + fr][kg];
      bl[f] = *(const half8*)&Bl[wc * 64 + f * 16 + fr][kg];
    }
#pragma unroll
    for (int fm = 0; fm < 4; ++fm)
#pragma unroll
      for (int fn = 0; fn < 4; ++fn) {
        acc[fm][fn] = __builtin_amdgcn_mfma_f32_16x16x32_f16(ah[fm], bh[fn], acc[fm][fn], 0, 0, 0);
        acc[fm][fn] = __builtin_amdgcn_mfma_f32_16x16x32_f16(ah[fm], bl[fn], acc[fm][fn], 0, 0, 0);
        acc[fm][fn] = __builtin_amdgcn_mfma_f32_16x16x32_f16(al[fm], bh[fn], acc[fm][fn], 0, 0, 0);
      }
  }
  const int rsub = (lane >> 4) << 2;
#pragma unroll
  for (int fm = 0; fm < 4; ++fm)
#pragma unroll
    for (int fn = 0; fn < 4; ++fn) {
      const int r0 = rowBase + wr * 64 + fm * 16 + rsub;
      const int c0 = colBase + wc * 64 + fn * 16 + fr;
#pragma unroll
      for (int r = 0; r < 4; ++r)
        Co[(size_t)(r0 + r) * P_CNT + c0] = acc[fm][fn][r];
    }
}

// ---------------- kernel STATS: streaming stats + LDS-buffered threshold appends ---
// 2048 blocks (8 slices x 256 samples) x 256 thr; global atomics: 2 reserves/block.
__global__ __launch_bounds__(256) void stats(
    const float* __restrict__ OUT, const int* __restrict__ cams,
    const int* __restrict__ prxArr,
    unsigned* __restrict__ maxKey, float* __restrict__ intraS,
    unsigned long long* __restrict__ camSlot,
    int* __restrict__ cxCnt, float* __restrict__ cxVal, int* __restrict__ cxIdx,
    int* __restrict__ smCnt, float* __restrict__ smVal, int* __restrict__ smIdx) {
  __shared__ float redM[4], redE[4];
  __shared__ float lVC[CAPB]; __shared__ int lIC[CAPB];
  __shared__ float lVS[CAPB]; __shared__ int lIS[CAPB];
  __shared__ int lcC, lcS, baseC, baseS;

  const int blk = blockIdx.x;
  const int b = blk >> 3, s = blk & 7;
  const int tid = threadIdx.x, lane = tid & 63, wid = tid >> 6;
  const float* Srow = OUT + (size_t)b * P_CNT + s * SLICE_N;
  const float* Mrow = OUT + (size_t)(B_SZ + b) * P_CNT + s * SLICE_N;
  const int pr = prxArr[b], cam = cams[b];
  const int posBase = pr & ~7;
  const int gbase = s * SLICE_N + 4 * tid;

  if (tid == 0) { lcC = 0; lcS = 0; }
  __syncthreads();

  // load score slice
  float sc[16];
#pragma unroll
  for (int q = 0; q < 4; ++q) {
    float4 f = ((const float4*)Srow)[tid + 256 * q];
    sc[4 * q + 0] = f.x; sc[4 * q + 1] = f.y; sc[4 * q + 2] = f.z; sc[4 * q + 3] = f.w;
  }
  float pmax = sc[0];
#pragma unroll
  for (int j = 1; j < 16; ++j) pmax = fmaxf(pmax, sc[j]);

  // intra partial: fixed-ref exp-sum over {p : p%8 == cam}
  float ei = 0.f;
  if ((tid & 1) == (cam >> 2)) {
    const int cc = cam & 3;
#pragma unroll
    for (int q = 0; q < 4; ++q) {
      float v = (cc == 0) ? sc[4 * q] : (cc == 1) ? sc[4 * q + 1]
              : (cc == 2) ? sc[4 * q + 2] : sc[4 * q + 3];
      ei += expf((v - MREF) * INVT);
    }
  }
#pragma unroll
  for (int off = 1; off < 64; off <<= 1) {
    pmax = fmaxf(pmax, __shfl_xor(pmax, off));
    ei += __shfl_xor(ei, off);
  }
  if (lane == 0) { redM[wid] = pmax; redE[wid] = ei; }

  // cross candidate appends -> LDS (score > TC, pos excluded)
#pragma unroll
  for (int j = 0; j < 16; ++j) {
    float v = sc[j];
    if (v > TC) {
      int p = gbase + ((j >> 2) << 10) + (j & 3);
      if ((unsigned)(p - posBase) >= 8u) {
        int t = atomicAdd(&lcC, 1);
        if (t < CAPB) { lVC[t] = v; lIC[t] = p; }
      }
    }
  }

  // sims
  float sm[16];
#pragma unroll
  for (int q = 0; q < 4; ++q) {
    float4 g = ((const float4*)Mrow)[tid + 256 * q];
    sm[4 * q + 0] = 0.15f * sc[4 * q + 0] + 0.85f * g.x;
    sm[4 * q + 1] = 0.15f * sc[4 * q + 1] + 0.85f * g.y;
    sm[4 * q + 2] = 0.15f * sc[4 * q + 2] + 0.85f * g.z;
    sm[4 * q + 3] = 0.15f * sc[4 * q + 3] + 0.85f * g.w;
  }
#pragma unroll
  for (int j = 0; j < 16; ++j) {
    float v = sm[j];
    if (v > TS) {
      int p = gbase + ((j >> 2) << 10) + (j & 3);
      int t = atomicAdd(&lcS, 1);
      if (t < CAPB) { lVS[t] = v; lIS[t] = p; }
    }
  }

  // per-cam argmax: exact via packed u64 (value, smaller index wins ties)
  {
    unsigned long long pk[4];
#pragma unroll
    for (int c = 0; c < 4; ++c) {
      float bv = sm[c]; int bp = gbase + c;
#pragma unroll
      for (int q = 1; q < 4; ++q) {
        float v = sm[4 * q + c];
        int p = gbase + (q << 10) + c;
        if (v > bv) { bv = v; bp = p; }
      }
      pk[c] = ((unsigned long long)fkey(bv) << 32) | (unsigned)(~(unsigned)bp);
    }
#pragma unroll
    for (int off = 2; off <= 32; off <<= 1) {
#pragma unroll
      for (int c = 0; c < 4; ++c) {
        unsigned long long o = __shfl_xor(pk[c], off);
        if (o > pk[c]) pk[c] = o;
      }
    }
    if (lane < 2) {
#pragma unroll
      for (int c = 0; c < 4; ++c)
        atomicMax(&camSlot[b * 8 + lane * 4 + c], pk[c]);
    }
  }
  __syncthreads();

  // single global reserve per list; overflow forces exact fixup
  if (tid == 0) {
    int n = min(lcC, CAPB);
    baseC = atomicAdd(&cxCnt[b], (lcC > CAPB) ? 1000000 : n);
    float m = fmaxf(fmaxf(redM[0], redM[1]), fmaxf(redM[2], redM[3]));
    atomicMax(&maxKey[b], fkey(m));
  }
  if (tid == 1) {
    int n = min(lcS, CAPB);
    baseS = atomicAdd(&smCnt[b], (lcS > CAPB) ? 1000000 : n);
    atomicAdd(&intraS[b], redE[0] + redE[1] + redE[2] + redE[3]);
  }
  __syncthreads();
  {
    const int nC = min(lcC, CAPB);
    for (int i = tid; i < nC; i += 256) {
      int o = baseC + i;
      if (o < CAPC) { cxVal[(size_t)b * CAPC + o] = lVC[i]; cxIdx[(size_t)b * CAPC + o] = lIC[i]; }
    }
    const int nS = min(lcS, CAPB);
    for (int i = tid; i < nS; i += 256) {
      int o = baseS + i;
      if (o < CAPS) { smVal[(size_t)b * CAPS + o] = lVS[i]; smIdx[(size_t)b * CAPS + o] = lIS[i]; }
    }
  }
}

// ---------------- helper: block count of elements above threshold -------------
__device__ int countAbove(const float* Srow, const float* Mrow, int mode,
                          float T, int posBase, int tid, int* redI) {
  int c = 0;
  for (int i = tid; i < P_CNT; i += 256) {
    float v = (mode == 0) ? Srow[i] : (0.15f * Srow[i] + 0.85f * Mrow[i]);
    bool ok = (mode == 0) ? ((unsigned)(i - posBase) >= 8u) : true;
    if (ok && v > T) c++;
  }
  return blockSumI4(c, tid, redI);
}

// ---------------- kernel FIXUP: exact fallback if counts out of range ---------
__global__ __launch_bounds__(256) void fixup(
    const float* __restrict__ OUT, const int* __restrict__ prxArr,
    const unsigned* __restrict__ maxKey,
    int* __restrict__ cxCnt, float* __restrict__ cxVal, int* __restrict__ cxIdx,
    int* __restrict__ smCnt, float* __restrict__ smVal, int* __restrict__ smIdx) {
  __shared__ int redI[4];
  const int b = blockIdx.x;
  const int tid = threadIdx.x;
  const float* Srow = OUT + (size_t)b * P_CNT;
  const float* Mrow = OUT + (size_t)(B_SZ + b) * P_CNT;
  const int posBase = prxArr[b] & ~7;

  int cc = cxCnt[b];
  if (cc < 50 || cc > CAPC) {
    float M = fdec(maxKey[b]);
    float lo = M - 1.0f;
    int c = countAbove(Srow, Mrow, 0, lo, posBase, tid, redI);
    for (int it = 0; it < 24 && c < 50; ++it) {
      lo -= (M - lo);
      c = countAbove(Srow, Mrow, 0, lo, posBase, tid, redI);
    }
    float hi = M;
    for (int it = 0; it < 32 && c > CAPC; ++it) {
      float mid = 0.5f * (lo + hi);
      int cm = countAbove(Srow, Mrow, 0, mid, posBase, tid, redI);
      if (cm >= 50) { lo = mid; c = cm; } else hi = mid;
    }
    if (tid == 0) cxCnt[b] = 0;
    __syncthreads();
    for (int i = tid; i < P_CNT; i += 256) {
      float v = Srow[i];
      if (v > lo && (unsigned)(i - posBase) >= 8u) {
        int t = atomicAdd(&cxCnt[b], 1);
        if (t < CAPC) { cxVal[(size_t)b * CAPC + t] = v; cxIdx[(size_t)b * CAPC + t] = i; }
      }
    }
    __syncthreads();
    if (tid == 0) { if (cxCnt[b] > CAPC) cxCnt[b] = CAPC; }
  }
  __syncthreads();

  int sc2 = smCnt[b];
  if (sc2 < 53 || sc2 > CAPS) {
    float mx = NEG_BIG;
    for (int i = tid; i < P_CNT; i += 256)
      mx = fmaxf(mx, 0.15f * Srow[i] + 0.85f * Mrow[i]);
#pragma unroll
    for (int off = 1; off < 64; off <<= 1) mx = fmaxf(mx, __shfl_xor(mx, off));
    if ((tid & 63) == 0) redI[tid >> 6] = __float_as_int(mx);
    __syncthreads();
    float M = fmaxf(fmaxf(__int_as_float(redI[0]), __int_as_float(redI[1])),
                    fmaxf(__int_as_float(redI[2]), __int_as_float(redI[3])));
    __syncthreads();
    float lo = M - 0.3f;
    int c = countAbove(Srow, Mrow, 1, lo, posBase, tid, redI);
    for (int it = 0; it < 24 && c < 53; ++it) {
      lo -= (M - lo);
      c = countAbove(Srow, Mrow, 1, lo, posBase, tid, redI);
    }
    float hi = M;
    for (int it = 0; it < 32 && c > CAPS; ++it) {
      float mid = 0.5f * (lo + hi);
      int cm = countAbove(Srow, Mrow, 1, mid, posBase, tid, redI);
      if (cm >= 53) { lo = mid; c = cm; } else hi = mid;
    }
    if (tid == 0) smCnt[b] = 0;
    __syncthreads();
    for (int i = tid; i < P_CNT; i += 256) {
      float v = 0.15f * Srow[i] + 0.85f * Mrow[i];
      if (v > lo) {
        int t = atomicAdd(&smCnt[b], 1);
        if (t < CAPS) { smVal[(size_t)b * CAPS + t] = v; smIdx[(size_t)b * CAPS + t] = i; }
      }
    }
    __syncthreads();
    if (tid == 0) { if (smCnt[b] > CAPS) smCnt[b] = CAPS; }
  }
}

// ---------------- kernel MERGE: per-sample exact rank + losses (256 blocks) ----
__global__ __launch_bounds__(256) void merge(
    const float* __restrict__ OUT, const int* __restrict__ prxArr,
    const unsigned* __restrict__ maxKey, const float* __restrict__ intraS,
    const unsigned long long* __restrict__ camSlot,
    const int* __restrict__ cxCnt, const float* __restrict__ cxVal,
    const int* __restrict__ cxIdx,
    const int* __restrict__ smCnt, const float* __restrict__ smVal,
    const int* __restrict__ smIdx,
    float* __restrict__ intraArr, float* __restrict__ crossArr,
    float* __restrict__ onlArr) {
  __shared__ __align__(16) float vb[CAPC + 4];
  __shared__ __align__(16) int   ib[CAPC + 4];
  __shared__ __align__(16) float vs[CAPS + 4];
  __shared__ __align__(16) int   is_[CAPS + 4];
  __shared__ float red4[4];
  __shared__ int ch[3];
  __shared__ float sbuf[56];
  __shared__ int scnt;

  const int b = blockIdx.x;
  const int tid = threadIdx.x;
  const float* Srow = OUT + (size_t)b * P_CNT;
  const int pr = prxArr[b];
  const int posBase = pr & ~7;
  const int C = min(cxCnt[b], CAPC);
  const int C2 = min(smCnt[b], CAPS);
  const int Cp = (C + 3) & ~3;
  const int C2p = (C2 + 3) & ~3;

  for (int i = tid; i < C; i += 256) {
    vb[i] = cxVal[(size_t)b * CAPC + i];
    ib[i] = cxIdx[(size_t)b * CAPC + i];
  }
  for (int i = tid; i < C2; i += 256) {
    vs[i] = smVal[(size_t)b * CAPS + i];
    is_[i] = smIdx[(size_t)b * CAPS + i];
  }
  if (tid >= 240 && tid < 244) {
    int i = C + (tid - 240);
    if (i < Cp) { vb[i] = NEG_BIG; ib[i] = 0x7fffffff; }
  }
  if (tid >= 244 && tid < 248) {
    int i = C2 + (tid - 244);
    if (i < C2p) { vs[i] = NEG_BIG; is_[i] = 0x7fffffff; }
  }
  if (tid == 96) {
    unsigned long long sl[8];
#pragma unroll
    for (int c = 0; c < 8; ++c) sl[c] = camSlot[b * 8 + c];
    unsigned used = 0;
    for (int k = 0; k < 3; ++k) {
      unsigned long long best = 0; int bc = 0;
      for (int c = 0; c < 8; ++c)
        if (!((used >> c) & 1u) && sl[c] > best) { best = sl[c]; bc = c; }
      used |= 1u << bc;
      ch[k] = (int)(~(unsigned)(best & 0xffffffffull));
    }
  }
  if (tid == 97) intraArr[b] = -((Srow[pr] - MREF) * INVT - logf(intraS[b]));
  if (tid == 98) scnt = 0;
  __syncthreads();

  const int c0 = ch[0], c1 = ch[1], c2 = ch[2];
  for (int i = tid; i < C2; i += 256) {
    int ix = is_[i];
    if (ix == c0 || ix == c1 || ix == c2) vs[i] = NEG_BIG;
  }
  __syncthreads();

  const float M = fdec(maxKey[b]);

  // sims rank -> winners gather
  {
    float v0 = (tid < C2) ? vs[tid] : NEG_BIG;
    int   i0 = (tid < C2) ? is_[tid] : 0x7fffffff;
    float v1 = (tid + 256 < C2) ? vs[tid + 256] : NEG_BIG;
    int   i1 = (tid + 256 < C2) ? is_[tid + 256] : 0x7fffffff;
    int r0 = 0, r1 = 0;
    const float4* v4 = (const float4*)vs;
    const int4*   q4 = (const int4*)is_;
    for (int m4 = 0; m4 < (C2p >> 2); ++m4) {
      float4 vm = v4[m4]; int4 im = q4[m4];
      r0 += (vm.x > v0) || (vm.x == v0 && im.x < i0);
      r0 += (vm.y > v0) || (vm.y == v0 && im.y < i0);
      r0 += (vm.z > v0) || (vm.z == v0 && im.z < i0);
      r0 += (vm.w > v0) || (vm.w == v0 && im.w < i0);
      r1 += (vm.x > v1) || (vm.x == v1 && im.x < i1);
      r1 += (vm.y > v1) || (vm.y == v1 && im.y < i1);
      r1 += (vm.z > v1) || (vm.z == v1 && im.z < i1);
      r1 += (vm.w > v1) || (vm.w == v1 && im.w < i1);
    }
    if (tid < C2 && v0 > -1.0e38f && r0 < 50) {
      int t = atomicAdd(&scnt, 1);
      if (t < 50) sbuf[t] = Srow[i0];
    }
    if (tid + 256 < C2 && v1 > -1.0e38f && r1 < 50) {
      int t = atomicAdd(&scnt, 1);
      if (t < 50) sbuf[t] = Srow[i1];
    }
    if (tid < 3) sbuf[50 + tid] = Srow[ch[tid]];
  }

  // cross rank -> exp-sum
  float myexp = 0.f, pl = 0.f;
  {
    float v0 = (tid < C) ? vb[tid] : NEG_BIG;
    int   i0 = (tid < C) ? ib[tid] : 0x7fffffff;
    float v1 = (tid + 256 < C) ? vb[tid + 256] : NEG_BIG;
    int   i1 = (tid + 256 < C) ? ib[tid + 256] : 0x7fffffff;
    int r0 = 0, r1 = 0;
    const float4* v4 = (const float4*)vb;
    const int4*   q4 = (const int4*)ib;
    for (int m4 = 0; m4 < (Cp >> 2); ++m4) {
      float4 vm = v4[m4]; int4 im = q4[m4];
      r0 += (vm.x > v0) || (vm.x == v0 && im.x < i0);
      r0 += (vm.y > v0) || (vm.y == v0 && im.y < i0);
      r0 += (vm.z > v0) || (vm.z == v0 && im.z < i0);
      r0 += (vm.w > v0) || (vm.w == v0 && im.w < i0);
      r1 += (vm.x > v1) || (vm.x == v1 && im.x < i1);
      r1 += (vm.y > v1) || (vm.y == v1 && im.y < i1);
      r1 += (vm.z > v1) || (vm.z == v1 && im.z < i1);
      r1 += (vm.w > v1) || (vm.w == v1 && im.w < i1);
    }
    if (tid < C && r0 < 50) myexp += expf((v0 - M) * INVT);
    if (tid + 256 < C && r1 < 50) myexp += expf((v1 - M) * INVT);
    if (tid < 8) {
      float pv = Srow[posBase + tid];
      myexp += expf((pv - M) * INVT);
      pl = (pv - M) * INVT;
    }
  }
  float stot = blockSum4(myexp, tid, red4);
  float plin = blockSum4(pl, tid, red4);
  if (tid == 0) {
    float lse = logf(stot);
    crossArr[b] = -(plin - 8.f * lse) * 0.125f;
  }

  if (tid < 64) {
    float v = (tid < 53) ? sbuf[tid] : NEG_BIG;
    float mm = v;
#pragma unroll
    for (int off = 1; off < 64; off <<= 1) mm = fmaxf(mm, __shfl_xor(mm, off));
    float e = (tid < 53) ? expf((v - mm) * INVT) : 0.f;
    float ss = e;
#pragma unroll
    for (int off = 1; off < 64; off <<= 1) ss += __shfl_xor(ss, off);
    float lse = logf(ss);
    float c = (tid >= 50 && tid < 53) ? ((v - mm) * INVT - lse) : 0.f;
#pragma unroll
    for (int off = 1; off < 64; off <<= 1) c += __shfl_xor(c, off);
    if (tid == 0) onlArr[b] = -c * (1.0f / 3.0f);
  }
}

// ---------------- kernel 3: per-camera means -> scalar ----------------
__global__ void finalize(const int* __restrict__ cams,
                         const float* __restrict__ ia,
                         const float* __restrict__ ca,
                         const float* __restrict__ oa,
                         float* __restrict__ out) {
  if (blockIdx.x == 0 && threadIdx.x == 0) {
    float s[8] = {}; float n[8] = {};
    for (int b = 0; b < B_SZ; ++b) {
      int c = cams[b];
      s[c] += ia[b] + ca[b] + oa[b];
      n[c] += 1.f;
    }
    float tot = 0.f;
    for (int c = 0; c < 8; ++c)
      if (n[c] > 0.f) tot += s[c] / n[c];
    out[0] = tot;
  }
}

extern "C" void kernel_launch(void* const* d_in, const int* in_sizes, int n_in,
                              void* d_out, int out_size, void* d_ws, size_t ws_size,
                              hipStream_t stream) {
  const float* features = (const float*)d_in[0];
  const int*   targets  = (const int*)d_in[1];
  const int*   cams     = (const int*)d_in[2];
  const float* mem      = (const float*)d_in[4];
  const int*   all_prx  = (const int*)d_in[6];

  float* ws = (float*)d_ws;
  float* A2  = ws;                               // 512*256
  float* OUT = ws + 512 * D_DIM;                 // 512*32768
  char*  tail = (char*)(OUT + (size_t)512 * P_CNT);

  int*      prxArr = (int*)tail;                tail += B_SZ * 4;
  char* zbase = tail;
  unsigned* maxKey = (unsigned*)tail;           tail += B_SZ * 4;
  float*    intraS = (float*)tail;              tail += B_SZ * 4;
  unsigned long long* camSlot = (unsigned long long*)tail; tail += B_SZ * 8 * 8;
  int* cxCnt = (int*)tail;                      tail += B_SZ * 4;
  int* smCnt = (int*)tail;                      tail += B_SZ * 4;
  size_t zbytes = (size_t)(tail - zbase);
  float* intraArr = (float*)tail;               tail += B_SZ * 4;
  float* crossArr = (float*)tail;               tail += B_SZ * 4;
  float* onlArr   = (float*)tail;               tail += B_SZ * 4;
  float* cxVal = (float*)tail;                  tail += (size_t)B_SZ * CAPC * 4;
  int*   cxIdx = (int*)tail;                    tail += (size_t)B_SZ * CAPC * 4;
  float* smVal = (float*)tail;                  tail += (size_t)B_SZ * CAPS * 4;
  int*   smIdx = (int*)tail;                    tail += (size_t)B_SZ * CAPS * 4;

  hipMemsetAsync(zbase, 0, zbytes, stream);
  prep_kernel<<<B_SZ, D_DIM, 0, stream>>>(features, targets, all_prx, mem, A2, prxArr);
  gemm_mfma<<<1024, 256, 0, stream>>>(A2, mem, OUT);
  stats<<<B_SZ * NSLICE, 256, 0, stream>>>(OUT, cams, prxArr,
      maxKey, intraS, camSlot, cxCnt, cxVal, cxIdx, smCnt, smVal, smIdx);
  fixup<<<B_SZ, 256, 0, stream>>>(OUT, prxArr, maxKey,
      cxCnt, cxVal, cxIdx, smCnt, smVal, smIdx);
  merge<<<B_SZ, 256, 0, stream>>>(OUT, prxArr, maxKey, intraS, camSlot,
      cxCnt, cxVal, cxIdx, smCnt, smVal, smIdx, intraArr, crossArr, onlArr);
  finalize<<<1, 64, 0, stream>>>(cams, intraArr, crossArr, onlArr, (float*)d_out);
}